// Round 1
// baseline (625.078 us; speedup 1.0000x reference)
//
#include <hip/hip_runtime.h>

// ---------------------------------------------------------------------------
// Whitening2d: B=32, S=2048, F=512, fp32 in/out.
//  out = (x - m) @ NS4(sigma)^; all heavy matmuls in bf16 MFMA (16x16x32),
//  fp32 accumulate. All B-operands are symmetric -> BT-form GEMM everywhere.
// ---------------------------------------------------------------------------

#define Bb 32
#define Ss 2048
#define Ff 512

typedef __attribute__((ext_vector_type(8))) short bf16x8;
typedef __attribute__((ext_vector_type(4))) float f32x4;

__device__ __forceinline__ unsigned short f2bf(float f) {
    unsigned int u = __float_as_uint(f);
    u += 0x7fffu + ((u >> 16) & 1u);   // round-to-nearest-even
    return (unsigned short)(u >> 16);
}

__device__ __forceinline__ void gload_lds16(const void* g, void* l) {
    __builtin_amdgcn_global_load_lds(
        (const __attribute__((address_space(1))) void*)g,
        (__attribute__((address_space(3))) void*)l,
        16, 0, 0);
}

// ---------------------------------------------------------------------------
// K1: partial sums over S for the per-(b,f) mean.  msum must be pre-zeroed.
// grid (32, 16), block 256
__global__ __launch_bounds__(256) void mean_kernel(const float* __restrict__ x,
                                                   float* __restrict__ msum) {
    int b = blockIdx.x, sc = blockIdx.y, t = threadIdx.x;
    const float* p = x + ((long)b * Ss + (long)sc * 128) * Ff;
    float a0 = 0.f, a1 = 0.f;
    for (int s = 0; s < 128; ++s) {
        a0 += p[(long)s * Ff + t];
        a1 += p[(long)s * Ff + t + 256];
    }
    atomicAdd(&msum[b * Ff + t], a0);
    atomicAdd(&msum[b * Ff + t + 256], a1);
}

// ---------------------------------------------------------------------------
// K2: xn = x - m (bf16), and xnT (bf16) via LDS tile transpose.
// grid (S/64=32, F/64=8, B=32), block 256
__global__ __launch_bounds__(256) void center_kernel(
    const float* __restrict__ x, const float* __restrict__ rm,
    const float* __restrict__ msum,
    unsigned short* __restrict__ xn, unsigned short* __restrict__ xnT) {
    __shared__ float tile[64][65];
    int b = blockIdx.z;
    int s0 = blockIdx.x * 64;
    int f0 = blockIdx.y * 64;
    int t = threadIdx.x;
    int fc = t & 63, sr = t >> 6;   // fc: 0..63, sr: 0..3
    float mv = 0.9f * rm[f0 + fc] + 0.1f * (msum[b * Ff + f0 + fc] * (1.0f / 2048.0f));
    const float* px = x + ((long)b * Ss + s0) * Ff + f0;
    unsigned short* pxn = xn + ((long)b * Ss + s0) * Ff + f0;
#pragma unroll
    for (int r = 0; r < 16; ++r) {
        int sl = sr + r * 4;
        float v = px[(long)sl * Ff + fc] - mv;
        tile[sl][fc] = v;
        pxn[(long)sl * Ff + fc] = f2bf(v);
    }
    __syncthreads();
    int sc = t & 63, fr = t >> 6;
    unsigned short* pT = xnT + ((long)b * Ff + f0) * Ss + s0;
#pragma unroll
    for (int r = 0; r < 16; ++r) {
        int fl = fr + r * 4;
        pT[(long)fl * Ss + sc] = f2bf(tile[sc][fl]);
    }
}

// ---------------------------------------------------------------------------
// K3: the workhorse BT-form GEMM.  C[m][n] = sum_k A[m][k] * Bt[n][k].
// 128x128 tile, BK=32, 256 threads (4 waves, 2x2 of 64x64), 16x16x32 bf16 MFMA.
// MODE 0: sigma   = 0.9*runcov + 0.1*(C/2047 + eps*I)           -> out32
// MODE 1: T       = bf16(C)                                      -> out16
// MODE 2: P       = 1.5*P32 - 0.5*C; write fp32 + bf16           -> out32,out16
// MODE 3: out     = C * scal[b]                                  -> out32
#define BM 128
#define BN 128
#define BK 32

template <int MODE>
__global__ __launch_bounds__(256, 3) void gemm_bt(
    const unsigned short* __restrict__ A, int lda, long strideA,
    const unsigned short* __restrict__ Bt, int ldb, long strideB,
    int K,
    const float* __restrict__ runcov,
    float* __restrict__ out32,
    unsigned short* __restrict__ out16,
    const float* __restrict__ scal,
    int ldc, long strideC) {
    __shared__ unsigned short sA[BM * BK];
    __shared__ unsigned short sB[BN * BK];
    int b = blockIdx.z;
    int m0 = blockIdx.x * BM;
    int n0 = blockIdx.y * BN;
    int t = threadIdx.x;
    int w = t >> 6, l = t & 63;
    int wm = (w >> 1) * 64, wn = (w & 1) * 64;

    const unsigned short* gA = A + (long)b * strideA;
    const unsigned short* gB = Bt + (long)b * strideB;

    // staging: thread t loads 16B: row t/4 (and +64), k-offset (t%4)*8
    int srow = t >> 2;
    int sk = (t & 3) * 8;
    const unsigned short* pa0 = gA + (long)(m0 + srow) * lda + sk;
    const unsigned short* pa1 = gA + (long)(m0 + 64 + srow) * lda + sk;
    const unsigned short* pb0 = gB + (long)(n0 + srow) * ldb + sk;
    const unsigned short* pb1 = gB + (long)(n0 + 64 + srow) * ldb + sk;
    unsigned short* la = &sA[srow * BK + sk];   // == sA + t*8 shorts (lane*16B)
    unsigned short* lb = &sB[srow * BK + sk];

    f32x4 acc[4][4] = {};
    int q = l >> 4, r16 = l & 15;
    const unsigned short* fa = &sA[(wm + r16) * BK + q * 8];
    const unsigned short* fb = &sB[(wn + r16) * BK + q * 8];

    for (int k0 = 0; k0 < K; k0 += BK) {
        gload_lds16(pa0, la);
        gload_lds16(pa1, la + 64 * BK);
        gload_lds16(pb0, lb);
        gload_lds16(pb1, lb + 64 * BK);
        pa0 += BK; pa1 += BK; pb0 += BK; pb1 += BK;
        __syncthreads();   // compiler emits s_waitcnt vmcnt(0) before barrier
        bf16x8 af[4], bf[4];
#pragma unroll
        for (int i = 0; i < 4; ++i) {
            af[i] = *reinterpret_cast<const bf16x8*>(fa + i * 16 * BK);
            bf[i] = *reinterpret_cast<const bf16x8*>(fb + i * 16 * BK);
        }
#pragma unroll
        for (int i = 0; i < 4; ++i)
#pragma unroll
            for (int j = 0; j < 4; ++j)
                acc[i][j] = __builtin_amdgcn_mfma_f32_16x16x32_bf16(
                    af[i], bf[j], acc[i][j], 0, 0, 0);
        __syncthreads();
    }

    // epilogue: C[row = wm+i*16+q*4+r][col = wn+j*16+r16]
    int mb = m0 + wm + q * 4;
    int nb = n0 + wn + r16;
#pragma unroll
    for (int i = 0; i < 4; ++i) {
#pragma unroll
        for (int j = 0; j < 4; ++j) {
#pragma unroll
            for (int r = 0; r < 4; ++r) {
                int m = mb + i * 16 + r;
                int n = nb + j * 16;
                long idx = (long)b * strideC + (long)m * ldc + n;
                float v = acc[i][j][r];
                if constexpr (MODE == 0) {
                    float rc = runcov[(long)m * ldc + n];
                    float d = (m == n) ? 1e-5f : 0.0f;
                    out32[idx] = 0.9f * rc + 0.1f * (v * (1.0f / 2047.0f) + d);
                } else if constexpr (MODE == 1) {
                    out16[idx] = f2bf(v);
                } else if constexpr (MODE == 2) {
                    float pn = 1.5f * out32[idx] - 0.5f * v;
                    out32[idx] = pn;
                    out16[idx] = f2bf(pn);
                } else {
                    out32[idx] = v * scal[b * 4 + 2];
                }
            }
        }
    }
}

// ---------------------------------------------------------------------------
// K4: per-batch trace of sigma + derived scalars {tr, 1/tr, 1/sqrt(tr)}.
// grid 32, block 256
__global__ __launch_bounds__(256) void trace_kernel(const float* __restrict__ sigma,
                                                    float* __restrict__ scal) {
    int b = blockIdx.x, t = threadIdx.x;
    const float* s = sigma + (long)b * Ff * Ff;
    float a = s[(long)t * (Ff + 1)] + s[(long)(t + 256) * (Ff + 1)];
    for (int o = 32; o > 0; o >>= 1) a += __shfl_down(a, o, 64);
    __shared__ float wsum[4];
    if ((t & 63) == 0) wsum[t >> 6] = a;
    __syncthreads();
    if (t == 0) {
        float tr = wsum[0] + wsum[1] + wsum[2] + wsum[3];
        scal[b * 4 + 0] = tr;
        scal[b * 4 + 1] = 1.0f / tr;
        scal[b * 4 + 2] = 1.0f / sqrtf(tr);
    }
}

// ---------------------------------------------------------------------------
// K5: S16 = bf16(sigma/tr); P = 1.5 I - 0.5 sigma/tr (fp32 + bf16).
// (this IS Newton-Schulz iteration 1, computed exactly: P0=I so P0^3*sn = sn)
// grid 8192, block 256 (4 elems/thread)
__global__ __launch_bounds__(256) void prep_kernel(
    const float* __restrict__ sigma, const float* __restrict__ scal,
    unsigned short* __restrict__ S16, float* __restrict__ P32,
    unsigned short* __restrict__ P16) {
    long idx = ((long)blockIdx.x * 256 + threadIdx.x) * 4;
    int b = (int)(idx >> 18);           // / (512*512)
    long rem = idx & 262143;
    int f = (int)(rem >> 9);
    int g0 = (int)(rem & 511);
    float it = scal[b * 4 + 1];
    float4 sv = *reinterpret_cast<const float4*>(&sigma[idx]);
    float s[4] = {sv.x, sv.y, sv.z, sv.w};
    ushort4 s16v, p16v;
    float4 p32v;
    float po[4];
#pragma unroll
    for (int r = 0; r < 4; ++r) {
        float sn = s[r] * it;
        float p = ((f == g0 + r) ? 1.5f : 0.0f) - 0.5f * sn;
        po[r] = p;
        ((unsigned short*)&s16v)[r] = f2bf(sn);
        ((unsigned short*)&p16v)[r] = f2bf(p);
    }
    p32v.x = po[0]; p32v.y = po[1]; p32v.z = po[2]; p32v.w = po[3];
    *reinterpret_cast<ushort4*>(&S16[idx]) = s16v;
    *reinterpret_cast<float4*>(&P32[idx]) = p32v;
    *reinterpret_cast<ushort4*>(&P16[idx]) = p16v;
}

// ---------------------------------------------------------------------------
extern "C" void kernel_launch(void* const* d_in, const int* in_sizes, int n_in,
                              void* d_out, int out_size, void* d_ws, size_t ws_size,
                              hipStream_t stream) {
    const float* x    = (const float*)d_in[0];
    const float* rm   = (const float*)d_in[1];
    const float* rcov = (const float*)d_in[2];
    float* out = (float*)d_out;

    char* ws = (char*)d_ws;
    // workspace layout (bytes)
    unsigned short* xn16  = (unsigned short*)(ws);                 // 64 MB
    unsigned short* xnT16 = (unsigned short*)(ws + 67108864L);     // 64 MB
    float*          sig32 = (float*)(ws + 134217728L);             // 32 MB
    float*          P32   = (float*)(ws + 167772160L);             // 32 MB
    unsigned short* S16   = (unsigned short*)(ws + 201326592L);    // 16 MB
    unsigned short* P16   = (unsigned short*)(ws + 218103808L);    // 16 MB
    unsigned short* T1    = (unsigned short*)(ws + 234881024L);    // 16 MB
    unsigned short* T2    = (unsigned short*)(ws + 251658240L);    // 16 MB
    float*          msum  = (float*)(ws + 268435456L);             // 64 KB
    float*          scal  = (float*)(ws + 268500992L);             // 512 B

    const long sFF = (long)Ff * Ff;        // 262144
    const long sSF = (long)Ss * Ff;        // 1048576

    hipMemsetAsync(msum, 0, Bb * Ff * sizeof(float), stream);
    mean_kernel<<<dim3(Bb, 16), 256, 0, stream>>>(x, msum);
    center_kernel<<<dim3(Ss / 64, Ff / 64, Bb), 256, 0, stream>>>(x, rm, msum, xn16, xnT16);

    // sigma = 0.9*rcov + 0.1*(xn^T xn /2047 + eps I)   (gram: A=Bt=xnT)
    gemm_bt<0><<<dim3(Ff / BM, Ff / BN, Bb), 256, 0, stream>>>(
        xnT16, Ss, sSF, xnT16, Ss, sSF, Ss, rcov, sig32, nullptr, nullptr, Ff, sFF);

    trace_kernel<<<Bb, 256, 0, stream>>>(sig32, scal);
    prep_kernel<<<(int)(Bb * sFF / 4 / 256), 256, 0, stream>>>(sig32, scal, S16, P32, P16);

    // Newton-Schulz iterations 2..4 (iteration 1 folded into prep)
    for (int it = 0; it < 3; ++it) {
        gemm_bt<1><<<dim3(Ff / BM, Ff / BN, Bb), 256, 0, stream>>>(
            P16, Ff, sFF, P16, Ff, sFF, Ff, nullptr, nullptr, T1, nullptr, Ff, sFF);
        gemm_bt<1><<<dim3(Ff / BM, Ff / BN, Bb), 256, 0, stream>>>(
            T1, Ff, sFF, P16, Ff, sFF, Ff, nullptr, nullptr, T2, nullptr, Ff, sFF);
        gemm_bt<2><<<dim3(Ff / BM, Ff / BN, Bb), 256, 0, stream>>>(
            T2, Ff, sFF, S16, Ff, sFF, Ff, nullptr, P32, P16, nullptr, Ff, sFF);
    }

    // out = (xn @ P4) / sqrt(tr)
    gemm_bt<3><<<dim3(Ss / BM, Ff / BN, Bb), 256, 0, stream>>>(
        xn16, Ff, sSF, P16, Ff, sFF, Ff, nullptr, out, nullptr, scal, Ff, sSF);
}

// Round 2
// 598.349 us; speedup vs baseline: 1.0447x; 1.0447x over previous
//
#include <hip/hip_runtime.h>

// ---------------------------------------------------------------------------
// Whitening2d: B=32, S=2048, F=512, fp32 in/out.
// Uncentered-Gram formulation:
//   G = x^T x (bf16 MFMA);  sigma_r = (G - n(mb m^T + m mb^T - m m^T))/(n-1)
//   out = (x@P - m@P) * tr^{-1/2}
// All heavy matmuls bf16 MFMA 16x16x32, fp32 accumulate, BT-form (symmetric B).
// ---------------------------------------------------------------------------

#define Bb 32
#define Ss 2048
#define Ff 512

typedef __attribute__((ext_vector_type(8))) short bf16x8;
typedef __attribute__((ext_vector_type(4))) float f32x4;

__device__ __forceinline__ unsigned short f2bf(float f) {
    unsigned int u = __float_as_uint(f);
    u += 0x7fffu + ((u >> 16) & 1u);   // RTNE
    return (unsigned short)(u >> 16);
}
__device__ __forceinline__ float bf2f(unsigned short u) {
    return __uint_as_float(((unsigned int)u) << 16);
}

__device__ __forceinline__ void gload_lds16(const void* g, void* l) {
    __builtin_amdgcn_global_load_lds(
        (const __attribute__((address_space(1))) void*)g,
        (__attribute__((address_space(3))) void*)l,
        16, 0, 0);
}

// ---------------------------------------------------------------------------
// K1: single pass over x: write x16 (bf16 cast), xT16 (bf16 transpose),
// and per-(b,stile,f) column-sum partials (no atomics).
// grid (32, 8, 32), block 256
__global__ __launch_bounds__(256) void cast_transpose(
    const float* __restrict__ x, unsigned short* __restrict__ x16,
    unsigned short* __restrict__ xT16, float* __restrict__ msum_p) {
    __shared__ float tile[64][65];
    __shared__ float psum[4][64];
    int b = blockIdx.z;
    int s0 = blockIdx.x * 64;
    int f0 = blockIdx.y * 64;
    int t = threadIdx.x, fc = t & 63, sr = t >> 6;
    const float* px = x + ((long)b * Ss + s0) * Ff + f0;
    unsigned short* p16 = x16 + ((long)b * Ss + s0) * Ff + f0;
    float lsum = 0.f;
#pragma unroll
    for (int r = 0; r < 16; ++r) {
        int sl = r * 4 + sr;
        float v = px[(long)sl * Ff + fc];
        tile[sl][fc] = v;
        p16[(long)sl * Ff + fc] = f2bf(v);
        lsum += v;
    }
    psum[sr][fc] = lsum;
    __syncthreads();
    if (t < 64)
        msum_p[((long)b * 32 + blockIdx.x) * Ff + f0 + t] =
            psum[0][t] + psum[1][t] + psum[2][t] + psum[3][t];
    int sc = t & 63, fr = t >> 6;
    unsigned short* pT = xT16 + ((long)b * Ff + f0) * Ss + s0;
#pragma unroll
    for (int r = 0; r < 16; ++r) {
        int fl = r * 4 + fr;
        pT[(long)fl * Ss + sc] = f2bf(tile[sc][fl]);
    }
}

// ---------------------------------------------------------------------------
// K2: reduce column-sum partials -> mbar (batch mean) and mv (blended mean).
// grid 32, block 256 (2 f per thread)
__global__ __launch_bounds__(256) void meanred(
    const float* __restrict__ msum_p, const float* __restrict__ rm,
    float* __restrict__ mbar, float* __restrict__ mv) {
    int b = blockIdx.x, t = threadIdx.x;
#pragma unroll
    for (int h = 0; h < 2; ++h) {
        int f = t + h * 256;
        float s = 0.f;
#pragma unroll 8
        for (int st = 0; st < 32; ++st) s += msum_p[((long)b * 32 + st) * Ff + f];
        float mb_ = s * (1.0f / 2048.0f);
        mbar[b * Ff + f] = mb_;
        mv[b * Ff + f] = 0.9f * rm[f] + 0.1f * mb_;
    }
}

// ---------------------------------------------------------------------------
// K3: BT-form GEMM.  C[m][n] = sum_k A[m][k] * Bt[n][k].
// 2x2 waves of (BM/2 x BN/2), BK=32, 16x16x32 bf16 MFMA.
// Grid is 1D, XCD-swizzled: batches cluster 4-per-XCD (lin&7 = XCD).
// MODE 0: sigma = 0.9*rcov + 0.1*((C-corr)/2047 + eps*I); trace->scal (atomic)
// MODE 1: bf16(C) -> out16
// MODE 2: P' = 1.5*P32 - 0.5*C -> out32 (P32) + out16 (P16)
// MODE 3: out = (C - vvec[n]) * rsqrt(tr)
#define BK 32

template <int MODE, int BM, int BN, int MT, int NT>
__global__ __launch_bounds__(256, (BN == 64 ? 4 : 3)) void gemm_bt(
    const unsigned short* __restrict__ A, int lda, long strideA,
    const unsigned short* __restrict__ Bt, int ldb, long strideB,
    int K,
    const float* __restrict__ runcov,
    float* __restrict__ out32,
    unsigned short* __restrict__ out16,
    const float* __restrict__ mbar,
    const float* __restrict__ mv,
    const float* __restrict__ vvec,
    float* __restrict__ scal,
    int ldc, long strideC) {
    constexpr int AR = BM / 64, BR = BN / 64;
    constexpr int WM = BM / 2, WN = BN / 2;
    constexpr int MI = WM / 16, NJ = WN / 16;
    constexpr int NTILES = MT * NT;
    constexpr int TB = (NTILES == 16) ? 4 : ((NTILES == 32) ? 5 : 6);
    __shared__ unsigned short sA[BM * BK];
    __shared__ unsigned short sB[BN * BK];

    int lin = blockIdx.x;
    int b = (lin & 7) * 4 + (lin >> (3 + TB));
    int tile = (lin >> 3) & (NTILES - 1);
    int m0 = (tile & (MT - 1)) * BM;
    int n0 = (tile / MT) * BN;

    int t = threadIdx.x;
    int w = t >> 6, l = t & 63;
    int wm = (w >> 1) * WM, wn = (w & 1) * WN;

    const unsigned short* gA = A + (long)b * strideA;
    const unsigned short* gB = Bt + (long)b * strideB;

    int srow = t >> 2, sk = (t & 3) * 8;
    const unsigned short* pa[AR];
    const unsigned short* pb[BR];
#pragma unroll
    for (int r = 0; r < AR; ++r) pa[r] = gA + (long)(m0 + r * 64 + srow) * lda + sk;
#pragma unroll
    for (int r = 0; r < BR; ++r) pb[r] = gB + (long)(n0 + r * 64 + srow) * ldb + sk;
    unsigned short* la = &sA[srow * BK + sk];
    unsigned short* lb = &sB[srow * BK + sk];

    f32x4 acc[MI][NJ] = {};
    int q = l >> 4, r16 = l & 15;
    const unsigned short* fa = &sA[(wm + r16) * BK + q * 8];
    const unsigned short* fb = &sB[(wn + r16) * BK + q * 8];

    for (int k0 = 0; k0 < K; k0 += BK) {
#pragma unroll
        for (int r = 0; r < AR; ++r) { gload_lds16(pa[r], la + r * 64 * BK); pa[r] += BK; }
#pragma unroll
        for (int r = 0; r < BR; ++r) { gload_lds16(pb[r], lb + r * 64 * BK); pb[r] += BK; }
        __syncthreads();
        bf16x8 af[MI], bf[NJ];
#pragma unroll
        for (int i = 0; i < MI; ++i)
            af[i] = *reinterpret_cast<const bf16x8*>(fa + i * 16 * BK);
#pragma unroll
        for (int j = 0; j < NJ; ++j)
            bf[j] = *reinterpret_cast<const bf16x8*>(fb + j * 16 * BK);
#pragma unroll
        for (int i = 0; i < MI; ++i)
#pragma unroll
            for (int j = 0; j < NJ; ++j)
                acc[i][j] = __builtin_amdgcn_mfma_f32_16x16x32_bf16(
                    af[i], bf[j], acc[i][j], 0, 0, 0);
        __syncthreads();
    }

    // epilogue: C[row = wm+i*16+q*4+r][col = wn+j*16+r16]
    int mb = m0 + wm + q * 4;
    int nb = n0 + wn + r16;
    long bF = (long)b * Ff;
    float rs = 0.f;
    if constexpr (MODE == 3) rs = 1.0f / sqrtf(scal[b]);
#pragma unroll
    for (int i = 0; i < MI; ++i) {
#pragma unroll
        for (int j = 0; j < NJ; ++j) {
#pragma unroll
            for (int r = 0; r < 4; ++r) {
                int m = mb + i * 16 + r;
                int n = nb + j * 16;
                long idx = (long)b * strideC + (long)m * ldc + n;
                float v = acc[i][j][r];
                if constexpr (MODE == 0) {
                    float bm_m = mbar[bF + m], bm_n = mbar[bF + n];
                    float mv_m = mv[bF + m], mv_n = mv[bF + n];
                    float corr = 2048.0f * (bm_m * mv_n + mv_m * bm_n - mv_m * mv_n);
                    float rc = runcov[(long)m * ldc + n];
                    float d = (m == n) ? 1e-5f : 0.0f;
                    float sig = 0.9f * rc + 0.1f * ((v - corr) * (1.0f / 2047.0f) + d);
                    out32[idx] = sig;
                    if (m == n) atomicAdd(&scal[b], sig);
                } else if constexpr (MODE == 1) {
                    out16[idx] = f2bf(v);
                } else if constexpr (MODE == 2) {
                    float pn = 1.5f * out32[idx] - 0.5f * v;
                    out32[idx] = pn;
                    out16[idx] = f2bf(pn);
                } else {
                    out32[idx] = (v - vvec[bF + n]) * rs;
                }
            }
        }
    }
}

// ---------------------------------------------------------------------------
// K4: S16 = bf16(sigma/tr); P = 1.5 I - 0.5 sigma/tr (fp32 + bf16).
// (NS iteration 1 computed exactly: P0=I)
__global__ __launch_bounds__(256) void prep_kernel(
    const float* __restrict__ sigma, const float* __restrict__ scal,
    unsigned short* __restrict__ S16, float* __restrict__ P32,
    unsigned short* __restrict__ P16) {
    long idx = ((long)blockIdx.x * 256 + threadIdx.x) * 4;
    int b = (int)(idx >> 18);
    long rem = idx & 262143;
    int f = (int)(rem >> 9);
    int g0 = (int)(rem & 511);
    float it = 1.0f / scal[b];
    float4 sv = *reinterpret_cast<const float4*>(&sigma[idx]);
    float s[4] = {sv.x, sv.y, sv.z, sv.w};
    ushort4 s16v, p16v;
    float4 p32v;
    float po[4];
#pragma unroll
    for (int r = 0; r < 4; ++r) {
        float sn = s[r] * it;
        float p = ((f == g0 + r) ? 1.5f : 0.0f) - 0.5f * sn;
        po[r] = p;
        ((unsigned short*)&s16v)[r] = f2bf(sn);
        ((unsigned short*)&p16v)[r] = f2bf(p);
    }
    p32v.x = po[0]; p32v.y = po[1]; p32v.z = po[2]; p32v.w = po[3];
    *reinterpret_cast<ushort4*>(&S16[idx]) = s16v;
    *reinterpret_cast<float4*>(&P32[idx]) = p32v;
    *reinterpret_cast<ushort4*>(&P16[idx]) = p16v;
}

// ---------------------------------------------------------------------------
// K5: vvec[b][n] = sum_k mv[b][k] * P16[b][k][n]   (tiny GEMV)
// grid (32, 2), block 256
__global__ __launch_bounds__(256) void mvecp(
    const float* __restrict__ mv, const unsigned short* __restrict__ P16,
    float* __restrict__ vvec) {
    int b = blockIdx.x;
    int n = blockIdx.y * 256 + threadIdx.x;
    const unsigned short* P = P16 + (long)b * Ff * Ff + n;
    const float* m = mv + (long)b * Ff;
    float a0 = 0.f, a1 = 0.f, a2 = 0.f, a3 = 0.f;
    for (int k = 0; k < Ff; k += 4) {
        a0 += m[k]     * bf2f(P[(long)k * Ff]);
        a1 += m[k + 1] * bf2f(P[(long)(k + 1) * Ff]);
        a2 += m[k + 2] * bf2f(P[(long)(k + 2) * Ff]);
        a3 += m[k + 3] * bf2f(P[(long)(k + 3) * Ff]);
    }
    vvec[(long)b * Ff + n] = (a0 + a1) + (a2 + a3);
}

// ---------------------------------------------------------------------------
extern "C" void kernel_launch(void* const* d_in, const int* in_sizes, int n_in,
                              void* d_out, int out_size, void* d_ws, size_t ws_size,
                              hipStream_t stream) {
    const float* x    = (const float*)d_in[0];
    const float* rm   = (const float*)d_in[1];
    const float* rcov = (const float*)d_in[2];
    float* out = (float*)d_out;

    char* ws = (char*)d_ws;
    unsigned short* x16   = (unsigned short*)(ws);                 // 64 MB
    unsigned short* xT16  = (unsigned short*)(ws + 67108864L);     // 64 MB
    float*          sig32 = (float*)(ws + 134217728L);             // 32 MB
    float*          P32   = (float*)(ws + 167772160L);             // 32 MB
    unsigned short* S16   = (unsigned short*)(ws + 201326592L);    // 16 MB
    unsigned short* P16   = (unsigned short*)(ws + 218103808L);    // 16 MB
    unsigned short* T1    = (unsigned short*)(ws + 234881024L);    // 16 MB
    unsigned short* T2    = (unsigned short*)(ws + 251658240L);    // 16 MB
    float*          msum_p= (float*)(ws + 268435456L);             // 2 MB
    float*          mbar  = (float*)(ws + 270532608L);             // 64 KB
    float*          mv    = (float*)(ws + 270598144L);             // 64 KB
    float*          vvec  = (float*)(ws + 270663680L);             // 64 KB
    float*          scal  = (float*)(ws + 270729216L);             // 128 B

    const long sFF = (long)Ff * Ff;        // 262144
    const long sSF = (long)Ss * Ff;        // 1048576

    hipMemsetAsync(scal, 0, Bb * sizeof(float), stream);
    cast_transpose<<<dim3(Ss / 64, Ff / 64, Bb), 256, 0, stream>>>(x, x16, xT16, msum_p);
    meanred<<<Bb, 256, 0, stream>>>(msum_p, rm, mbar, mv);

    // sigma (Gram of raw x + fp32 rank-1 correction), trace -> scal
    gemm_bt<0, 128, 128, 4, 4><<<512, 256, 0, stream>>>(
        xT16, Ss, sSF, xT16, Ss, sSF, Ss, rcov, sig32, nullptr,
        mbar, mv, nullptr, scal, Ff, sFF);

    prep_kernel<<<(int)(Bb * sFF / 4 / 256), 256, 0, stream>>>(sig32, scal, S16, P32, P16);

    // Newton-Schulz iterations 2..4 (iteration 1 folded into prep)
    for (int it = 0; it < 3; ++it) {
        gemm_bt<1, 128, 64, 4, 8><<<1024, 256, 0, stream>>>(
            P16, Ff, sFF, P16, Ff, sFF, Ff, nullptr, nullptr, T1,
            nullptr, nullptr, nullptr, nullptr, Ff, sFF);
        gemm_bt<1, 128, 64, 4, 8><<<1024, 256, 0, stream>>>(
            T1, Ff, sFF, P16, Ff, sFF, Ff, nullptr, nullptr, T2,
            nullptr, nullptr, nullptr, nullptr, Ff, sFF);
        gemm_bt<2, 128, 64, 4, 8><<<1024, 256, 0, stream>>>(
            T2, Ff, sFF, S16, Ff, sFF, Ff, nullptr, P32, P16,
            nullptr, nullptr, nullptr, nullptr, Ff, sFF);
    }

    mvecp<<<dim3(Bb, 2), 256, 0, stream>>>(mv, P16, vvec);

    // out = (x@P - mv@P) * tr^{-1/2}
    gemm_bt<3, 128, 128, 16, 4><<<2048, 256, 0, stream>>>(
        x16, Ff, sSF, P16, Ff, sFF, Ff, nullptr, out, nullptr,
        nullptr, nullptr, vvec, scal, Ff, sSF);
}

// Round 3
// 586.339 us; speedup vs baseline: 1.0661x; 1.0205x over previous
//
#include <hip/hip_runtime.h>

// ---------------------------------------------------------------------------
// Whitening2d: B=32, S=2048, F=512, fp32 in/out.
// Uncentered-Gram + commuting-polynomial Newton-Schulz:
//   G = x^T x;  sigma = 0.9 rcov + 0.1 ((G - rank1corr)/2047 + eps I)
//   sn = sigma/tr;  P1 = 1.5I - 0.5 sn          (exact, ref's I-matmuls exact)
//   W = sn^2 (GEMM); T = 2.25I -1.5 sn +0.25 W; U = 1.5 sn -0.5 W  (elementwise)
//   P2 = 1.5 P1 - 0.5 T*U (GEMM)
//   iter 3,4: {T=P^2, U=P*sn} (dual GEMM) ; P' = 1.5P - 0.5 T*U (GEMM epi)
//   out = (x@P4 - mv@P4) * tr^{-1/2}
// ---------------------------------------------------------------------------

#define Bb 32
#define Ss 2048
#define Ff 512

typedef __attribute__((ext_vector_type(8))) short bf16x8;
typedef __attribute__((ext_vector_type(4))) float f32x4;

__device__ __forceinline__ unsigned short f2bf(float f) {
    unsigned int u = __float_as_uint(f);
    u += 0x7fffu + ((u >> 16) & 1u);   // RTNE
    return (unsigned short)(u >> 16);
}
__device__ __forceinline__ float bf2f(unsigned short u) {
    return __uint_as_float(((unsigned int)u) << 16);
}
__device__ __forceinline__ ushort4 f4bf(float4 v) {
    ushort4 h;
    h.x = f2bf(v.x); h.y = f2bf(v.y); h.z = f2bf(v.z); h.w = f2bf(v.w);
    return h;
}

__device__ __forceinline__ void gload_lds16(const void* g, void* l) {
    __builtin_amdgcn_global_load_lds(
        (const __attribute__((address_space(1))) void*)g,
        (__attribute__((address_space(3))) void*)l,
        16, 0, 0);
}

// ---------------------------------------------------------------------------
// K1: one pass over x: x16 (bf16), xT16 (bf16 transpose via LDS), col-sums.
// grid (32, 8, 32), block 256. All LDS scalar ops <=2-way bank alias (free).
__global__ __launch_bounds__(256) void cast_transpose(
    const float* __restrict__ x, unsigned short* __restrict__ x16,
    unsigned short* __restrict__ xT16, float* __restrict__ msum_p) {
    __shared__ float tT[64][65];     // [f][s], pad 65: scalar r/w conflict-free
    __shared__ float psum[16][64];
    int b = blockIdx.z;
    int s0 = blockIdx.x * 64;
    int f0 = blockIdx.y * 64;
    int t = threadIdx.x;
    int fg = t & 15, sr = t >> 4;    // fg: f-chunk 0..15, sr: 0..15
    const float* px = x + ((long)b * Ss + s0) * Ff + f0;
    unsigned short* p16 = x16 + ((long)b * Ss + s0) * Ff + f0;
    float sm0 = 0.f, sm1 = 0.f, sm2 = 0.f, sm3 = 0.f;
#pragma unroll
    for (int r = 0; r < 4; ++r) {
        int s = r * 16 + sr;
        float4 v = *reinterpret_cast<const float4*>(px + (long)s * Ff + fg * 4);
        *reinterpret_cast<ushort4*>(p16 + (long)s * Ff + fg * 4) = f4bf(v);
        tT[fg * 4 + 0][s] = v.x;
        tT[fg * 4 + 1][s] = v.y;
        tT[fg * 4 + 2][s] = v.z;
        tT[fg * 4 + 3][s] = v.w;
        sm0 += v.x; sm1 += v.y; sm2 += v.z; sm3 += v.w;
    }
    *reinterpret_cast<float4*>(&psum[sr][fg * 4]) = make_float4(sm0, sm1, sm2, sm3);
    __syncthreads();
    if (t < 64) {
        float a = 0.f;
#pragma unroll
        for (int i = 0; i < 16; ++i) a += psum[i][t];
        msum_p[((long)b * 32 + blockIdx.x) * Ff + f0 + t] = a;
    }
    // phase 2: transposed store, rows of tT -> 8B/lane
    int sg = t & 15, fr0 = t >> 4;
    unsigned short* pT = xT16 + ((long)b * Ff + f0) * Ss + s0;
#pragma unroll
    for (int r = 0; r < 4; ++r) {
        int f = r * 16 + fr0;
        float4 v = make_float4(tT[f][sg * 4], tT[f][sg * 4 + 1],
                               tT[f][sg * 4 + 2], tT[f][sg * 4 + 3]);
        *reinterpret_cast<ushort4*>(pT + (long)f * Ss + sg * 4) = f4bf(v);
    }
}

// ---------------------------------------------------------------------------
// K2: reduce col-sum partials -> mbar (batch mean), mv (blended mean).
__global__ __launch_bounds__(256) void meanred(
    const float* __restrict__ msum_p, const float* __restrict__ rm,
    float* __restrict__ mbar, float* __restrict__ mv) {
    int b = blockIdx.x, t = threadIdx.x;
#pragma unroll
    for (int h = 0; h < 2; ++h) {
        int f = t + h * 256;
        float s = 0.f;
#pragma unroll 8
        for (int st = 0; st < 32; ++st) s += msum_p[((long)b * 32 + st) * Ff + f];
        float mb_ = s * (1.0f / 2048.0f);
        mbar[b * Ff + f] = mb_;
        mv[b * Ff + f] = 0.9f * rm[f] + 0.1f * mb_;
    }
}

// ---------------------------------------------------------------------------
// K3: BT-form GEMM.  C[m][n] = sum_k A[m][k] * Bt[n][k].
// 1D grid, XCD batch clustering (lin&7 = XCD, 4 batches/XCD).
// MODE 0: sigma epilogue + trace atomic   -> out32 (sig), scal
// MODE 1: out16 = bf16(C)                 (DUAL: half grid uses A2/B2/out16b)
// MODE 2: P' = 1.5*out32 - 0.5C           -> out32 (rw), out16
// MODE 3: out = (C - vvec[n]) * rsqrt(tr) -> out32
// MODE 4: p1 = 1.5I - 0.5*aux32/tr; P'=1.5p1-0.5C -> out32, out16
// MODE 5: out32 = C
#define BK 32

template <int MODE, int BM, int BN, int MT, int NT, bool DUAL>
__global__ __launch_bounds__(256, (BN == 64 ? 4 : 3)) void gemm_bt(
    const unsigned short* __restrict__ A, int lda, long strideA,
    const unsigned short* __restrict__ Bt, int ldb, long strideB,
    const unsigned short* __restrict__ A2, const unsigned short* __restrict__ B2,
    int K,
    const float* __restrict__ aux32,
    float* __restrict__ out32,
    unsigned short* __restrict__ out16,
    unsigned short* __restrict__ out16b,
    const float* __restrict__ mbar,
    const float* __restrict__ mv,
    const float* __restrict__ vvec,
    float* __restrict__ scal,
    int ldc, long strideC) {
    constexpr int AR = BM / 64, BR = BN / 64;
    constexpr int WM = BM / 2, WN = BN / 2;
    constexpr int MI = WM / 16, NJ = WN / 16;
    constexpr int NTILES = MT * NT;
    constexpr int TB = (NTILES == 16) ? 4 : ((NTILES == 32) ? 5 : 6);
    __shared__ unsigned short sA[BM * BK];
    __shared__ unsigned short sB[BN * BK];

    int lin = blockIdx.x;
    bool sel = false;
    if constexpr (DUAL) {
        int half = gridDim.x >> 1;
        sel = lin >= half;
        if (sel) lin -= half;
    }
    int b = (lin & 7) * 4 + (lin >> (3 + TB));
    int tile = (lin >> 3) & (NTILES - 1);
    int m0 = (tile & (MT - 1)) * BM;
    int n0 = (tile / MT) * BN;

    int t = threadIdx.x;
    int w = t >> 6, l = t & 63;
    int wm = (w >> 1) * WM, wn = (w & 1) * WN;

    const unsigned short* Ap = (DUAL && sel) ? A2 : A;
    const unsigned short* Bp = (DUAL && sel) ? B2 : Bt;
    unsigned short* o16 = (DUAL && sel) ? out16b : out16;

    const unsigned short* gA = Ap + (long)b * strideA;
    const unsigned short* gB = Bp + (long)b * strideB;

    int srow = t >> 2, sk = (t & 3) * 8;
    const unsigned short* pa[AR];
    const unsigned short* pb[BR];
#pragma unroll
    for (int r = 0; r < AR; ++r) pa[r] = gA + (long)(m0 + r * 64 + srow) * lda + sk;
#pragma unroll
    for (int r = 0; r < BR; ++r) pb[r] = gB + (long)(n0 + r * 64 + srow) * ldb + sk;
    unsigned short* la = &sA[srow * BK + sk];
    unsigned short* lb = &sB[srow * BK + sk];

    f32x4 acc[MI][NJ] = {};
    int q = l >> 4, r16 = l & 15;
    const unsigned short* fa = &sA[(wm + r16) * BK + q * 8];
    const unsigned short* fb = &sB[(wn + r16) * BK + q * 8];

    for (int k0 = 0; k0 < K; k0 += BK) {
#pragma unroll
        for (int r = 0; r < AR; ++r) { gload_lds16(pa[r], la + r * 64 * BK); pa[r] += BK; }
#pragma unroll
        for (int r = 0; r < BR; ++r) { gload_lds16(pb[r], lb + r * 64 * BK); pb[r] += BK; }
        __syncthreads();
        bf16x8 af[MI], bf[NJ];
#pragma unroll
        for (int i = 0; i < MI; ++i)
            af[i] = *reinterpret_cast<const bf16x8*>(fa + i * 16 * BK);
#pragma unroll
        for (int j = 0; j < NJ; ++j)
            bf[j] = *reinterpret_cast<const bf16x8*>(fb + j * 16 * BK);
#pragma unroll
        for (int i = 0; i < MI; ++i)
#pragma unroll
            for (int j = 0; j < NJ; ++j)
                acc[i][j] = __builtin_amdgcn_mfma_f32_16x16x32_bf16(
                    af[i], bf[j], acc[i][j], 0, 0, 0);
        __syncthreads();
    }

    // epilogue: C[row = wm+i*16+q*4+r][col = wn+j*16+r16]
    int mb = m0 + wm + q * 4;
    int nb = n0 + wn + r16;
    long bF = (long)b * Ff;
    float rs = 0.f, invtr = 0.f;
    if constexpr (MODE == 3) rs = 1.0f / sqrtf(scal[b]);
    if constexpr (MODE == 4) invtr = 1.0f / scal[b];
#pragma unroll
    for (int i = 0; i < MI; ++i) {
#pragma unroll
        for (int j = 0; j < NJ; ++j) {
#pragma unroll
            for (int r = 0; r < 4; ++r) {
                int m = mb + i * 16 + r;
                int n = nb + j * 16;
                long idx = (long)b * strideC + (long)m * ldc + n;
                float v = acc[i][j][r];
                if constexpr (MODE == 0) {
                    float bm_m = mbar[bF + m], bm_n = mbar[bF + n];
                    float mv_m = mv[bF + m], mv_n = mv[bF + n];
                    float corr = 2048.0f * (bm_m * mv_n + mv_m * bm_n - mv_m * mv_n);
                    float rc = aux32[(long)m * ldc + n];
                    float d = (m == n) ? 1e-5f : 0.0f;
                    float sig = 0.9f * rc + 0.1f * ((v - corr) * (1.0f / 2047.0f) + d);
                    out32[idx] = sig;
                    if (m == n) atomicAdd(&scal[b], sig);
                } else if constexpr (MODE == 1) {
                    o16[idx] = f2bf(v);
                } else if constexpr (MODE == 2) {
                    float pn = 1.5f * out32[idx] - 0.5f * v;
                    out32[idx] = pn;
                    out16[idx] = f2bf(pn);
                } else if constexpr (MODE == 3) {
                    out32[idx] = (v - vvec[bF + n]) * rs;
                } else if constexpr (MODE == 4) {
                    float p1 = ((m == n) ? 1.5f : 0.0f) - 0.5f * aux32[idx] * invtr;
                    float pn = 1.5f * p1 - 0.5f * v;
                    out32[idx] = pn;
                    out16[idx] = f2bf(pn);
                } else {
                    out32[idx] = v;
                }
            }
        }
    }
}

// ---------------------------------------------------------------------------
// K4: S16 = bf16(sigma/tr).  8 elems/thread, grid 4096.
__global__ __launch_bounds__(256) void prep_kernel(
    const float* __restrict__ sigma, const float* __restrict__ scal,
    unsigned short* __restrict__ S16) {
    long idx = ((long)blockIdx.x * 256 + threadIdx.x) * 8;
    int b = (int)(idx >> 18);
    float it = 1.0f / scal[b];
    float4 s0 = *reinterpret_cast<const float4*>(&sigma[idx]);
    float4 s1 = *reinterpret_cast<const float4*>(&sigma[idx + 4]);
    ushort4 h0, h1;
    h0.x = f2bf(s0.x * it); h0.y = f2bf(s0.y * it);
    h0.z = f2bf(s0.z * it); h0.w = f2bf(s0.w * it);
    h1.x = f2bf(s1.x * it); h1.y = f2bf(s1.y * it);
    h1.z = f2bf(s1.z * it); h1.w = f2bf(s1.w * it);
    *reinterpret_cast<ushort4*>(&S16[idx]) = h0;
    *reinterpret_cast<ushort4*>(&S16[idx + 4]) = h1;
}

// ---------------------------------------------------------------------------
// K5: T16 = bf16(2.25I -1.5 sn +0.25 W), U16 = bf16(1.5 sn -0.5 W).
// sn = sigma/tr (fp32), W = sn^2 (fp32 GEMM out).  4 elems/thread.
__global__ __launch_bounds__(256) void ew_tu(
    const float* __restrict__ sigma, const float* __restrict__ W,
    const float* __restrict__ scal,
    unsigned short* __restrict__ T16, unsigned short* __restrict__ U16) {
    long idx = ((long)blockIdx.x * 256 + threadIdx.x) * 4;
    int b = (int)(idx >> 18);
    long rem = idx & 262143;
    int f = (int)(rem >> 9);
    int g0 = (int)(rem & 511);
    float it = 1.0f / scal[b];
    float4 sv = *reinterpret_cast<const float4*>(&sigma[idx]);
    float4 wv = *reinterpret_cast<const float4*>(&W[idx]);
    float s[4] = {sv.x, sv.y, sv.z, sv.w};
    float wq[4] = {wv.x, wv.y, wv.z, wv.w};
    ushort4 tv, uv;
#pragma unroll
    for (int r = 0; r < 4; ++r) {
        float sn = s[r] * it;
        float d = (f == g0 + r) ? 2.25f : 0.0f;
        ((unsigned short*)&tv)[r] = f2bf(d - 1.5f * sn + 0.25f * wq[r]);
        ((unsigned short*)&uv)[r] = f2bf(1.5f * sn - 0.5f * wq[r]);
    }
    *reinterpret_cast<ushort4*>(&T16[idx]) = tv;
    *reinterpret_cast<ushort4*>(&U16[idx]) = uv;
}

// ---------------------------------------------------------------------------
// K6: vvec[b][n] = sum_k mv[b][k] * P16[b][k][n]
__global__ __launch_bounds__(256) void mvecp(
    const float* __restrict__ mv, const unsigned short* __restrict__ P16,
    float* __restrict__ vvec) {
    int b = blockIdx.x;
    int n = blockIdx.y * 256 + threadIdx.x;
    const unsigned short* P = P16 + (long)b * Ff * Ff + n;
    const float* m = mv + (long)b * Ff;
    float a0 = 0.f, a1 = 0.f, a2 = 0.f, a3 = 0.f;
    for (int k = 0; k < Ff; k += 4) {
        a0 += m[k]     * bf2f(P[(long)k * Ff]);
        a1 += m[k + 1] * bf2f(P[(long)(k + 1) * Ff]);
        a2 += m[k + 2] * bf2f(P[(long)(k + 2) * Ff]);
        a3 += m[k + 3] * bf2f(P[(long)(k + 3) * Ff]);
    }
    vvec[(long)b * Ff + n] = (a0 + a1) + (a2 + a3);
}

// ---------------------------------------------------------------------------
extern "C" void kernel_launch(void* const* d_in, const int* in_sizes, int n_in,
                              void* d_out, int out_size, void* d_ws, size_t ws_size,
                              hipStream_t stream) {
    const float* x    = (const float*)d_in[0];
    const float* rm   = (const float*)d_in[1];
    const float* rcov = (const float*)d_in[2];
    float* out = (float*)d_out;

    char* ws = (char*)d_ws;
    unsigned short* x16   = (unsigned short*)(ws);                 // 64 MB
    unsigned short* xT16  = (unsigned short*)(ws + 67108864L);     // 64 MB
    float*          sig32 = (float*)(ws + 134217728L);             // 32 MB
    float*          P32   = (float*)(ws + 167772160L);             // 32 MB
    unsigned short* S16   = (unsigned short*)(ws + 201326592L);    // 16 MB
    unsigned short* P16   = (unsigned short*)(ws + 218103808L);    // 16 MB
    unsigned short* T16   = (unsigned short*)(ws + 234881024L);    // 16 MB
    unsigned short* U16   = (unsigned short*)(ws + 251658240L);    // 16 MB
    float*          msum_p= (float*)(ws + 268435456L);             // 2 MB
    float*          mbar  = (float*)(ws + 270532608L);             // 64 KB
    float*          mv    = (float*)(ws + 270598144L);             // 64 KB
    float*          vvec  = (float*)(ws + 270663680L);             // 64 KB
    float*          scal  = (float*)(ws + 270729216L);             // 128 B
    float*          W32   = (float*)d_out;  // 32 MB scratch, overwritten by final

    const long sFF = (long)Ff * Ff;
    const long sSF = (long)Ss * Ff;

    hipMemsetAsync(scal, 0, Bb * sizeof(float), stream);
    cast_transpose<<<dim3(Ss / 64, Ff / 64, Bb), 256, 0, stream>>>(x, x16, xT16, msum_p);
    meanred<<<Bb, 256, 0, stream>>>(msum_p, rm, mbar, mv);

    // sigma + trace
    gemm_bt<0, 128, 128, 4, 4, false><<<512, 256, 0, stream>>>(
        xT16, Ss, sSF, xT16, Ss, sSF, nullptr, nullptr, Ss,
        rcov, sig32, nullptr, nullptr, mbar, mv, nullptr, scal, Ff, sFF);

    prep_kernel<<<4096, 256, 0, stream>>>(sig32, scal, S16);

    // G1: W = sn^2
    gemm_bt<5, 128, 64, 4, 8, false><<<1024, 256, 0, stream>>>(
        S16, Ff, sFF, S16, Ff, sFF, nullptr, nullptr, Ff,
        nullptr, W32, nullptr, nullptr, nullptr, nullptr, nullptr, nullptr, Ff, sFF);
    // T,U elementwise (iter-2 operands)
    ew_tu<<<8192, 256, 0, stream>>>(sig32, W32, scal, T16, U16);
    // G2: P2 = 1.5 P1 - 0.5 T*U   (P1 from sigma inline)
    gemm_bt<4, 128, 64, 4, 8, false><<<1024, 256, 0, stream>>>(
        T16, Ff, sFF, U16, Ff, sFF, nullptr, nullptr, Ff,
        sig32, P32, P16, nullptr, nullptr, nullptr, nullptr, scal, Ff, sFF);

    // iters 3,4: dual {T=P^2, U=P*sn} then V=T*U with P-update epilogue
    for (int it = 0; it < 2; ++it) {
        gemm_bt<1, 128, 64, 4, 8, true><<<2048, 256, 0, stream>>>(
            P16, Ff, sFF, P16, Ff, sFF, P16, S16, Ff,
            nullptr, nullptr, T16, U16, nullptr, nullptr, nullptr, nullptr, Ff, sFF);
        gemm_bt<2, 128, 64, 4, 8, false><<<1024, 256, 0, stream>>>(
            T16, Ff, sFF, U16, Ff, sFF, nullptr, nullptr, Ff,
            nullptr, P32, P16, nullptr, nullptr, nullptr, nullptr, nullptr, Ff, sFF);
    }

    mvecp<<<dim3(Bb, 2), 256, 0, stream>>>(mv, P16, vvec);

    // out = (x@P4 - mv@P4) * tr^{-1/2}
    gemm_bt<3, 128, 128, 16, 4, false><<<2048, 256, 0, stream>>>(
        x16, Ff, sSF, P16, Ff, sFF, nullptr, nullptr, Ff,
        nullptr, out, nullptr, nullptr, nullptr, nullptr, vvec, scal, Ff, sSF);
}